// Round 1
// 435.652 us; speedup vs baseline: 1.0021x; 1.0021x over previous
//
#include <hip/hip_runtime.h>
#include <hip/hip_bf16.h>
#include <math.h>

// ---------------------------------------------------------------------------
// LSV Monte Carlo, round 7.
// R6 was VALU-issue bound (72% busy) at a structural 50% occupancy cap:
// 256 blocks x 16 waves = 1 block/CU, so barrier skew + trans latency had
// nothing to hide under. Changes:
//  * 512 blocks x 512 threads (8 waves, 32 paths/block) -> 2 blocks/CU.
//    Same total work; the two barrier groups interleave on each CU.
//    pt = w&1 (2 path tiles), jg/hm = w>>1. Lanes 32-63 mirror paths 0-31.
//  * Per-step uniforms (t0,h,sqh,disc0,disc1,idx,im) precomputed once into
//    LDS tables (identical fp expressions -> identical numerics); saves
//    2 exp + 1 sqrt + int chain per thread-step.
//  * Hedge bias baked into MFMA C operand (no SDE feedback on that path);
//    epilogue b2/w3 hoisted to registers; VD/VV nets on waves 0/1 (hm=0,
//    hedge-idle after day 24) instead of the always-busy hm=3 waves.
//  * finalize: 84 blocks x 64 lanes, coalesced + butterfly (was 1 block,
//    serial stride-256 loads: ~tens of us of straggler time).
// ---------------------------------------------------------------------------

#define MC      16384
#define NSTEP   96
#define BLOCK   512
#define NGROUP  512
#define NPAIR   84

typedef short bf16x8 __attribute__((ext_vector_type(8)));
typedef float f32x4  __attribute__((ext_vector_type(4)));

union U8 { uint4 u; bf16x8 v; };
union BF2U { __hip_bfloat162 b; unsigned u; };

__device__ __forceinline__ unsigned bf16rne(float x) {   // setup-time only
    unsigned u = __float_as_uint(x);
    return (u + 0x7FFFu + ((u >> 16) & 1u)) >> 16;
}
__device__ __forceinline__ unsigned pk2(float lo, float hi) {
    BF2U t; t.b = __float22bfloat162_rn(make_float2(lo, hi));
    return t.u;
}
__device__ __forceinline__ float sp(float x) {
    return fmaxf(x, 0.f) + __logf(1.f + __expf(-fabsf(x)));
}

__global__ __launch_bounds__(BLOCK, 4)
void lsv_sim(const float* __restrict__ S0p,   const float* __restrict__ ratep,
             const float* __restrict__ z,     const float* __restrict__ zzg,
             const float* __restrict__ strikesg,
             const float* __restrict__ v0p,   const float* __restrict__ rhop,
             const float* __restrict__ svW1,  const float* __restrict__ svb1,
             const float* __restrict__ svW2,  const float* __restrict__ svb2,
             const float* __restrict__ svW3,  const float* __restrict__ svb3,
             const float* __restrict__ vhW1,  const float* __restrict__ vhb1,
             const float* __restrict__ vhW2,  const float* __restrict__ vhb2,
             const float* __restrict__ vdW1,  const float* __restrict__ vdb1,
             const float* __restrict__ vdW2,  const float* __restrict__ vdb2,
             const float* __restrict__ vvW1,  const float* __restrict__ vvb1,
             const float* __restrict__ vvW2,  const float* __restrict__ vvb2,
             const int*   __restrict__ mats,
             float* __restrict__ psum, float* __restrict__ psq)
{
    __shared__ __align__(16) unsigned short H1c[16 * 32 * 8]; // 8 KB [kchunk][path][8]
    __shared__ __align__(16) float W1f[16 * 32];              // 2 KB  [kc]{wa8,wb8,wc8,bias8}
    __shared__ __align__(16) float WH1f[16 * 32];             // 2 KB  [hm*4+quad]{wt8,ws8,bb8,pad8}
    __shared__ __align__(16) float B2T[128], W3T[128];        // 1 KB
    __shared__ __align__(16) float RED[32 * 4];               // [path][jg]
    __shared__ __align__(16) float VDl[2][32], VVl[2][32];
    __shared__ __align__(16) float PSs[2][32], PSq[2][32];
    __shared__ __align__(16) float VW[128];
    __shared__ __align__(16) float4 STEP[NSTEP];              // {t0, h, sqh, disc0}
    __shared__ float D1T[NSTEP];                              // disc1
    __shared__ int   ITAB[NSTEP];                             // idx | (im<<8)

    const int tid  = threadIdx.x;
    const int lane = tid & 63;
    const int w    = __builtin_amdgcn_readfirstlane(tid >> 6);
    const int quad = lane >> 4;
    const int col  = lane & 15;
    const int lp   = lane & 31;                // local path (lanes 32-63 mirror)
    const int gpath = blockIdx.x * 32 + lp;

    const int pt = w & 1;      // path tile (both GEMMs)
    const int jg = w >> 1;     // main: j-group 0..3 (j-tiles 2jg, 2jg+1)
    const int hm = w >> 1;     // hedge: maturity

    // ---- stage LDS tables --------------------------------------------------
    for (int e = tid; e < 128; e += BLOCK) {
        float v = 0.f;
        if      (e < 20)             v = vdW1[e];
        else if (e < 40)             v = vdb1[e - 20];
        else if (e < 60)             v = vdW2[e - 40];
        else if (e >= 64 && e < 84)  v = vvW1[e - 64];
        else if (e >= 84 && e < 104) v = vvb1[e - 84];
        else if (e >= 104 && e < 124)v = vvW2[e - 104];
        else if (e == 124)           v = vdb2[0];
        else if (e == 125)           v = vvb2[0];
        VW[e] = v;
        B2T[e] = (e < 100) ? svb2[e] : 0.f;
        W3T[e] = (e < 100) ? svW3[e] : 0.f;
    }
    for (int e = tid; e < 512; e += BLOCK) {       // W1f
        const int kc2 = e >> 5, r5 = e & 31, grp = r5 >> 3, kk = kc2 * 8 + (r5 & 7);
        float v = 0.f;
        if (kk < 100) v = (grp == 0) ? svW1[kk] : (grp == 1) ? svW1[100 + kk]
                        : (grp == 2) ? svW1[200 + kk] : svb1[kk];
        W1f[e] = v;
    }
    for (int e = tid; e < 512; e += BLOCK) {       // WH1f
        const int hq = e >> 5, r5 = e & 31, grp = r5 >> 3;
        const int hmm = hq >> 2, qq = hq & 3;
        const int j = qq * 8 + (r5 & 7);
        float v = 0.f;
        if (j < 20 && grp < 3)
            v = (grp == 0) ? vhW1[hmm * 40 + j] : (grp == 1) ? vhW1[hmm * 40 + 20 + j]
                                                : vhb1[hmm * 20 + j];
        WH1f[e] = v;
    }

    // ---- uniform setup -----------------------------------------------------
    const float rate  = ratep[0];
    const float S0    = S0p[0];
    const float rho_t = tanhf(rhop[0]);
    const float srho  = sqrtf(1.f - rho_t * rho_t);
    const float b3    = svb3[0];

    // ---- per-step uniform tables (identical fp expressions to R6) ----------
    if (tid < NSTEP) {
        const int i = tid;
        const float t0 = (float)i       * (1.f / 365.f);
        const float t1 = (float)(i + 1) * (1.f / 365.f);
        const float h  = t1 - t0;
        STEP[i] = make_float4(t0, h, sqrtf(h), __expf(-rate * t0));
        D1T[i]  = __expf(-rate * t1);
        const int day = i + 1;
        const int m0 = mats[0], m1 = mats[1], m2 = mats[2], m3 = mats[3];
        const int idx = (day > m0) + (day > m1) + (day > m2);
        const int mi  = (idx == 0) ? m0 : (idx == 1) ? m1 : (idx == 2) ? m2 : m3;
        ITAB[i] = idx | ((day == mi) ? 256 : 0);
    }

    // ---- invariant A-fragments (weights) -----------------------------------
    // main: A[m=j][k], j = (2jg+t)*16 + col, k = 32c + 8quad + e
    bf16x8 Af[4][2];
#pragma unroll
    for (int c = 0; c < 4; c++)
#pragma unroll
        for (int t = 0; t < 2; t++) {
            U8 tt;
#pragma unroll
            for (int e2 = 0; e2 < 4; e2++) {
                const int k0 = 32 * c + 8 * quad + 2 * e2;
                const int j  = (2 * jg + t) * 16 + col;
                const float v0 = (k0     < 100 && j < 100) ? svW2[k0 * 100 + j]       : 0.f;
                const float v1 = (k0 + 1 < 100 && j < 100) ? svW2[(k0 + 1) * 100 + j] : 0.f;
                (&tt.u.x)[e2] = bf16rne(v0) | (bf16rne(v1) << 16);
            }
            Af[c][t] = tt.v;
        }
    // hedge: A[m=s][k=j], s = st*16 + col, j = 8quad + e
    bf16x8 Ah[2];
#pragma unroll
    for (int st = 0; st < 2; st++) {
        U8 tt;
#pragma unroll
        for (int e2 = 0; e2 < 4; e2++) {
            const int j0 = 8 * quad + 2 * e2, j1 = j0 + 1;
            const int s  = st * 16 + col;
            const float v0 = (j0 < 20 && s < 21) ? vhW2[hm * 420 + j0 * 21 + s] : 0.f;
            const float v1 = (j1 < 20 && s < 21) ? vhW2[hm * 420 + j1 * 21 + s] : 0.f;
            (&tt.u.x)[e2] = bf16rne(v0) | (bf16rne(v1) << 16);
        }
        Ah[st] = tt.v;
    }
    // hedge per-lane D-row constants; biases go into MFMA C operand
    f32x4 c0h, c1h;
    float K0a[4], K1a[4];
#pragma unroll
    for (int r = 0; r < 4; r++) {
        const int s0 = quad * 4 + r, s1 = 16 + quad * 4 + r;
        c0h[r] = vhb2[hm * 21 + s0];
        K0a[r] = strikesg[s0];
        c1h[r] = (s1 < 21) ? vhb2[hm * 21 + s1] : 0.f;
        K1a[r] = (s1 < 21) ? strikesg[s1] : 1e30f;
    }

    // ---- per-path state (lane&31 = path, redundant across waves) -----------
    float Slog = __logf(S0);
    float S    = __expf(Slog);
    float V    = (1.f / (1.f + __expf(-v0p[0]))) * 0.5f;
    f32x4 cv0 = {0.f, 0.f, 0.f, 0.f};
    f32x4 cv1 = {0.f, 0.f, 0.f, 0.f};
    float Slog_prev = 0.f, dS_prev = 0.f;

    const float* zrow  = z   + (size_t)gpath * NSTEP;
    const float* zzrow = zzg + (size_t)gpath * NSTEP;

    const int path = pt * 16 + col;        // P1/B-frag path of this thread
    const int kc   = jg * 4 + quad;        // P1 k-chunk of this thread

    __syncthreads();

    // invariant epilogue constants -> registers (staged LDS is stable now)
    const int j0e = (2 * jg) * 16 + quad * 4;
    const float4 b2a = *reinterpret_cast<const float4*>(B2T + j0e);
    const float4 w3a = *reinterpret_cast<const float4*>(W3T + j0e);
    const float4 b2b = *reinterpret_cast<const float4*>(B2T + j0e + 16);
    const float4 w3b = *reinterpret_cast<const float4*>(W3T + j0e + 16);

    auto hedge_step = [&](int ip) {
        const int iv   = ITAB[ip];
        const int idxp = iv & 0xff;
        if (hm >= idxp) {
            const float t0p = STEP[ip].x;
            const float slp = __shfl(Slog_prev, path);
            U8 b;
#pragma unroll
            for (int hh = 0; hh < 2; hh++) {
                const float* Wp = WH1f + (hm * 4 + quad) * 32 + hh * 4;
                const float4 wt4 = *reinterpret_cast<const float4*>(Wp);
                const float4 ws4 = *reinterpret_cast<const float4*>(Wp + 8);
                const float4 bb4 = *reinterpret_cast<const float4*>(Wp + 16);
                const float x0 = fmaxf(bb4.x + t0p * wt4.x + slp * ws4.x, 0.f);
                const float x1 = fmaxf(bb4.y + t0p * wt4.y + slp * ws4.y, 0.f);
                const float x2 = fmaxf(bb4.z + t0p * wt4.z + slp * ws4.z, 0.f);
                const float x3 = fmaxf(bb4.w + t0p * wt4.w + slp * ws4.w, 0.f);
                (&b.u.x)[2 * hh]     = pk2(x0, x1);
                (&b.u.x)[2 * hh + 1] = pk2(x2, x3);
            }
            const f32x4 D0 = __builtin_amdgcn_mfma_f32_16x16x32_bf16(Ah[0], b.v, c0h, 0, 0, 0);
            const f32x4 D1 = __builtin_amdgcn_mfma_f32_16x16x32_bf16(Ah[1], b.v, c1h, 0, 0, 0);
            const float dsP = __shfl(dS_prev, path);
#pragma unroll
            for (int r = 0; r < 4; r++) {
                cv0[r] += sp(D0[r]) * dsP;
                cv1[r] += sp(D1[r]) * dsP;
            }
            if ((iv & 256) && hm == idxp) {
                const float Sp   = __shfl(S, path);
                const float d1p  = D1T[ip];
                float p0[4], q0[4], p1[4], q1[4];
#pragma unroll
                for (int r = 0; r < 4; r++) {
                    p0[r] = d1p * fmaxf(Sp - K0a[r], 0.f) - cv0[r];
                    p1[r] = d1p * fmaxf(Sp - K1a[r], 0.f) - cv1[r];
                    q0[r] = p0[r] * p0[r];
                    q1[r] = p1[r] * p1[r];
                }
#pragma unroll
                for (int o = 1; o <= 8; o <<= 1) {
#pragma unroll
                    for (int r = 0; r < 4; r++) {
                        p0[r] += __shfl_xor(p0[r], o);
                        q0[r] += __shfl_xor(q0[r], o);
                        p1[r] += __shfl_xor(p1[r], o);
                        q1[r] += __shfl_xor(q1[r], o);
                    }
                }
                if (col == 0) {
#pragma unroll
                    for (int r = 0; r < 4; r++) {
                        const int s0 = quad * 4 + r, s1 = 16 + quad * 4 + r;
                        PSs[pt][s0] = p0[r];  PSq[pt][s0] = q0[r];
                        if (s1 < 21) { PSs[pt][s1] = p1[r];  PSq[pt][s1] = q1[r]; }
                    }
                }
            }
        }
    };

    auto ps_reduce = [&](int ip) {
        if (w == 0) {
            const int iv = ITAB[ip];
            if (iv & 256) {
                const int s = lane & 31;
                if (s < 21) {
                    const float* src = (lane >= 32) ? &PSq[0][0] : &PSs[0][0];
                    const float acc = src[s] + src[32 + s];
                    float* dst = (lane >= 32) ? psq : psum;
                    dst[((iv & 0xff) * 21 + s) * NGROUP + blockIdx.x] = acc;
                }
            }
        }
    };

    for (int i = 0; i < NSTEP; i++) {
        const float zi  = zrow[i];
        const float zzi = zzrow[i];
        const float4 u  = STEP[i];          // {t0, h, sqh, disc0}

        // ===== Region 1: P1 h1 chunk | lagged hedge | vd/vv nets ============
        {
            const float slp = __shfl(Slog, path);
            const float vp  = __shfl(V, path);
            const float t0  = u.x;
            const float* Wp = W1f + kc * 32;
            uint4 o;
#pragma unroll
            for (int hh = 0; hh < 2; hh++) {
                const float4 a4 = *reinterpret_cast<const float4*>(Wp + hh * 4);
                const float4 b4 = *reinterpret_cast<const float4*>(Wp + 8 + hh * 4);
                const float4 c4 = *reinterpret_cast<const float4*>(Wp + 16 + hh * 4);
                const float4 d4 = *reinterpret_cast<const float4*>(Wp + 24 + hh * 4);
                const float x0 = fmaxf(d4.x + t0 * a4.x + slp * b4.x + vp * c4.x, 0.f);
                const float x1 = fmaxf(d4.y + t0 * a4.y + slp * b4.y + vp * c4.y, 0.f);
                const float x2 = fmaxf(d4.z + t0 * a4.z + slp * b4.z + vp * c4.z, 0.f);
                const float x3 = fmaxf(d4.w + t0 * a4.w + slp * b4.w + vp * c4.w, 0.f);
                (&o.x)[2 * hh]     = pk2(x0, x1);
                (&o.x)[2 * hh + 1] = pk2(x2, x3);
            }
            *reinterpret_cast<uint4*>(H1c + (kc * 32 + path) * 8) = o;
        }
        if (i > 0) hedge_step(i - 1);
        if (w == 0) {                         // v-drift net (hm=0 wave: idle after day 24)
            float a2 = 0.f;
#pragma unroll
            for (int q5 = 0; q5 < 5; q5++) {
                const float4 w1 = *reinterpret_cast<const float4*>(VW + 4 * q5);
                const float4 b1 = *reinterpret_cast<const float4*>(VW + 20 + 4 * q5);
                const float4 w2 = *reinterpret_cast<const float4*>(VW + 40 + 4 * q5);
                a2 += fmaxf(V * w1.x + b1.x, 0.f) * w2.x;
                a2 += fmaxf(V * w1.y + b1.y, 0.f) * w2.y;
                a2 += fmaxf(V * w1.z + b1.z, 0.f) * w2.z;
                a2 += fmaxf(V * w1.w + b1.w, 0.f) * w2.w;
            }
            if (lane < 32) VDl[i & 1][lane] = a2;
        }
        if (w == 1) {                         // v-vol net
            float a2 = 0.f;
#pragma unroll
            for (int q5 = 0; q5 < 5; q5++) {
                const float4 w1 = *reinterpret_cast<const float4*>(VW + 64 + 4 * q5);
                const float4 b1 = *reinterpret_cast<const float4*>(VW + 84 + 4 * q5);
                const float4 w2 = *reinterpret_cast<const float4*>(VW + 104 + 4 * q5);
                a2 += fmaxf(V * w1.x + b1.x, 0.f) * w2.x;
                a2 += fmaxf(V * w1.y + b1.y, 0.f) * w2.y;
                a2 += fmaxf(V * w1.z + b1.z, 0.f) * w2.z;
                a2 += fmaxf(V * w1.w + b1.w, 0.f) * w2.w;
            }
            if (lane < 32) VVl[i & 1][lane] = a2;
        }
        __syncthreads();

        // ===== Region 2: main MFMA (A=W2T inv, B=h1) + per-lane epilogue ====
        {
            f32x4 d0 = {0.f, 0.f, 0.f, 0.f};
            f32x4 d1 = {0.f, 0.f, 0.f, 0.f};
#pragma unroll
            for (int c = 0; c < 4; c++) {
                const bf16x8 b = *reinterpret_cast<const bf16x8*>(
                    H1c + ((quad + 4 * c) * 32 + path) * 8);
                d0 = __builtin_amdgcn_mfma_f32_16x16x32_bf16(Af[c][0], b, d0, 0, 0, 0);
                d1 = __builtin_amdgcn_mfma_f32_16x16x32_bf16(Af[c][1], b, d1, 0, 0, 0);
            }
            float acc = fmaxf(d0[0] + b2a.x, 0.f) * w3a.x
                      + fmaxf(d0[1] + b2a.y, 0.f) * w3a.y
                      + fmaxf(d0[2] + b2a.z, 0.f) * w3a.z
                      + fmaxf(d0[3] + b2a.w, 0.f) * w3a.w
                      + fmaxf(d1[0] + b2b.x, 0.f) * w3b.x
                      + fmaxf(d1[1] + b2b.y, 0.f) * w3b.y
                      + fmaxf(d1[2] + b2b.z, 0.f) * w3b.z
                      + fmaxf(d1[3] + b2b.w, 0.f) * w3b.w;
            acc += __shfl_xor(acc, 16);
            acc += __shfl_xor(acc, 32);
            if (quad == 0)
                RED[path * 4 + jg] = acc;
        }
        if (i > 0) ps_reduce(i - 1);
        __syncthreads();

        // ===== Region 3: SDE tail (redundant per wave, state in regs) =======
        {
            const float4 rr = *reinterpret_cast<const float4*>(RED + lp * 4);
            const float pout = (rr.x + rr.y) + (rr.z + rr.w);
            const float pd = sp(pout + b3);
            const float vdv = VDl[i & 1][lp] + VW[124];
            const float vvv = sp(VVl[i & 1][lp] + VW[125]);
            const float sqh = u.z;
            const float dW = sqh * zi;
            const float dB = rho_t * dW + srho * sqh * zzi;
            const float Vn = V + vdv * u.y + vvv * dB;
            const float drift   = rate - 0.5f * pd * pd;
            const float diff    = pd * dW;
            const float drift_c = 1.f + fabsf(drift) * sqh;
            const float diff_c  = 1.f + fabsf(pd) * sqh;
            const float Sln = Slog + __fdividef(drift * u.y, drift_c) + __fdividef(diff, diff_c);
            const float Sn  = __expf(Sln);
            const float dS  = D1T[i] * Sn - u.w * S;
            Slog_prev = Slog; dS_prev = dS;
            Slog = Sln; S = Sn; V = Vn;
        }
    }

    hedge_step(NSTEP - 1);
    __syncthreads();
    ps_reduce(NSTEP - 1);
}

__global__ void lsv_finalize(const float* __restrict__ psum,
                             const float* __restrict__ psq,
                             float* __restrict__ out)
{
    const int t    = blockIdx.x;          // 0..NPAIR-1
    const int lane = threadIdx.x;         // 0..63
    float s = 0.f, q = 0.f;
    for (int b = lane; b < NGROUP; b += 64) {
        s += psum[t * NGROUP + b];
        q += psq [t * NGROUP + b];
    }
#pragma unroll
    for (int o = 1; o <= 32; o <<= 1) {
        s += __shfl_xor(s, o);
        q += __shfl_xor(q, o);
    }
    if (lane == 0) {
        const float mean = s * (1.0f / (float)MC);
        const float var  = (q - (float)MC * mean * mean) * (1.0f / (float)(MC - 1));
        out[t]         = mean;
        out[NPAIR + t] = var;
    }
}

extern "C" void kernel_launch(void* const* d_in, const int* in_sizes, int n_in,
                              void* d_out, int out_size, void* d_ws, size_t ws_size,
                              hipStream_t stream)
{
    const float* S0    = (const float*)d_in[0];
    const float* rate  = (const float*)d_in[1];
    const float* z     = (const float*)d_in[2];
    const float* zz    = (const float*)d_in[3];
    const float* strikes = (const float*)d_in[5];
    const float* v0    = (const float*)d_in[6];
    const float* rho   = (const float*)d_in[7];
    const float* svW1  = (const float*)d_in[8];
    const float* svb1  = (const float*)d_in[9];
    const float* svW2  = (const float*)d_in[10];
    const float* svb2  = (const float*)d_in[11];
    const float* svW3  = (const float*)d_in[12];
    const float* svb3  = (const float*)d_in[13];
    const float* vhW1  = (const float*)d_in[14];
    const float* vhb1  = (const float*)d_in[15];
    const float* vhW2  = (const float*)d_in[16];
    const float* vhb2  = (const float*)d_in[17];
    const float* vdW1  = (const float*)d_in[18];
    const float* vdb1  = (const float*)d_in[19];
    const float* vdW2  = (const float*)d_in[20];
    const float* vdb2  = (const float*)d_in[21];
    const float* vvW1  = (const float*)d_in[22];
    const float* vvb1  = (const float*)d_in[23];
    const float* vvW2  = (const float*)d_in[24];
    const float* vvb2  = (const float*)d_in[25];
    const int*   mats  = (const int*)d_in[26];

    float* psum = (float*)d_ws;
    float* psq  = psum + NPAIR * NGROUP;

    hipLaunchKernelGGL(lsv_sim, dim3(NGROUP), dim3(BLOCK), 0, stream,
                       S0, rate, z, zz, strikes, v0, rho,
                       svW1, svb1, svW2, svb2, svW3, svb3,
                       vhW1, vhb1, vhW2, vhb2,
                       vdW1, vdb1, vdW2, vdb2,
                       vvW1, vvb1, vvW2, vvb2,
                       mats, psum, psq);

    hipLaunchKernelGGL(lsv_finalize, dim3(NPAIR), dim3(64), 0, stream,
                       psum, psq, (float*)d_out);
}

// Round 2
// 392.313 us; speedup vs baseline: 1.1128x; 1.1105x over previous
//
#include <hip/hip_runtime.h>
#include <hip/hip_bf16.h>
#include <math.h>

// ---------------------------------------------------------------------------
// LSV Monte Carlo, round 8.
// R6->R7 (same per-CU issue, different block shape) changed NOTHING ->
// kernel is aggregate-issue bound (VALU+trans), not barrier/occupancy bound.
// So: delete instructions.
//  * R3 (SDE tail) was executed redundantly by all 16 waves/CU. Now: path
//    state lives in LDS (SLOG/VST/SST/SLOGP/DSP); only wave 1 runs R3, in a
//    third phase. All __shfl(state,path) -> conflict-free LDS b32 reads.
//  * z/zz prestaged to LDS [32][97] (padded: conflict-free read+write);
//    removes 2 global loads/thread-step.
//  * t0-folding: per-step tables CW1 = fma(t0,wa,bias) (W1 net) and
//    CH = fma(t0,wt,bb) (hedge L1), double-buffered, computed for step i+1
//    by waves 2-5 during phase C (idle there). Saves 8 FMA + loads in both
//    P1 and hedge. fma(t0,a,d) is bit-identical to the old chain head.
//  * vd/vv nets merged onto wave 0 (lane<32 = vd, lane>=32 = vv).
// Cost: 3 barriers/step instead of 2.
// ---------------------------------------------------------------------------

#define MC      16384
#define NSTEP   96
#define BLOCK   512
#define NGROUP  512
#define NPAIR   84

typedef short bf16x8 __attribute__((ext_vector_type(8)));
typedef float f32x4  __attribute__((ext_vector_type(4)));

union U8 { uint4 u; bf16x8 v; };
union BF2U { __hip_bfloat162 b; unsigned u; };

__device__ __forceinline__ unsigned bf16rne(float x) {   // setup-time only
    unsigned u = __float_as_uint(x);
    return (u + 0x7FFFu + ((u >> 16) & 1u)) >> 16;
}
__device__ __forceinline__ unsigned pk2(float lo, float hi) {
    BF2U t; t.b = __float22bfloat162_rn(make_float2(lo, hi));
    return t.u;
}
__device__ __forceinline__ float sp(float x) {
    return fmaxf(x, 0.f) + __logf(1.f + __expf(-fabsf(x)));
}

__global__ __launch_bounds__(BLOCK, 4)
void lsv_sim(const float* __restrict__ S0p,   const float* __restrict__ ratep,
             const float* __restrict__ z,     const float* __restrict__ zzg,
             const float* __restrict__ strikesg,
             const float* __restrict__ v0p,   const float* __restrict__ rhop,
             const float* __restrict__ svW1,  const float* __restrict__ svb1,
             const float* __restrict__ svW2,  const float* __restrict__ svb2,
             const float* __restrict__ svW3,  const float* __restrict__ svb3,
             const float* __restrict__ vhW1,  const float* __restrict__ vhb1,
             const float* __restrict__ vhW2,  const float* __restrict__ vhb2,
             const float* __restrict__ vdW1,  const float* __restrict__ vdb1,
             const float* __restrict__ vdW2,  const float* __restrict__ vdb2,
             const float* __restrict__ vvW1,  const float* __restrict__ vvb1,
             const float* __restrict__ vvW2,  const float* __restrict__ vvb2,
             const int*   __restrict__ mats,
             float* __restrict__ psum, float* __restrict__ psq)
{
    __shared__ __align__(16) unsigned short H1c[16 * 32 * 8]; // 8 KB
    __shared__ __align__(16) float W1f[16 * 32];              // 2 KB
    __shared__ __align__(16) float WH1f[16 * 32];             // 2 KB
    __shared__ __align__(16) float B2T[128], W3T[128];        // 1 KB
    __shared__ __align__(16) float RED[32 * 4];
    __shared__ float VDl[32], VVl[32];
    __shared__ float PSs[2][32], PSq[2][32];
    __shared__ __align__(16) float VW[128];
    __shared__ __align__(16) float4 STEP[NSTEP];              // {t0, h, sqh, disc0}
    __shared__ float D1T[NSTEP];                              // disc1
    __shared__ int   ITAB[NSTEP];                             // idx | (im<<8)
    __shared__ float ZT[32][97], ZZT[32][97];                 // 24.8 KB, padded
    __shared__ float SLOG[32], VST[32], SST[32], SLOGP[32], DSP[32];
    __shared__ __align__(16) float CW1[2][128];               // t0-fold: W1 net
    __shared__ __align__(16) float CH[2][128];                // t0-fold: hedge L1

    const int tid  = threadIdx.x;
    const int lane = tid & 63;
    const int w    = __builtin_amdgcn_readfirstlane(tid >> 6);
    const int quad = lane >> 4;
    const int col  = lane & 15;
    const int lp   = lane & 31;                // local path

    const int pt = w & 1;      // path tile (both GEMMs)
    const int jg = w >> 1;     // main: j-group 0..3
    const int hm = w >> 1;     // hedge: maturity

    // ---- stage z/zz into LDS (fully coalesced global reads) ----------------
    {
        const size_t gbase = (size_t)blockIdx.x * 32 * NSTEP;
        for (int e = tid; e < 32 * NSTEP; e += BLOCK) {
            const int p = e / NSTEP, ii = e - p * NSTEP;
            ZT[p][ii]  = z  [gbase + e];
            ZZT[p][ii] = zzg[gbase + e];
        }
    }
    // ---- stage LDS tables --------------------------------------------------
    for (int e = tid; e < 128; e += BLOCK) {
        float v = 0.f;
        if      (e < 20)             v = vdW1[e];
        else if (e < 40)             v = vdb1[e - 20];
        else if (e < 60)             v = vdW2[e - 40];
        else if (e >= 64 && e < 84)  v = vvW1[e - 64];
        else if (e >= 84 && e < 104) v = vvb1[e - 84];
        else if (e >= 104 && e < 124)v = vvW2[e - 104];
        else if (e == 124)           v = vdb2[0];
        else if (e == 125)           v = vvb2[0];
        VW[e] = v;
        B2T[e] = (e < 100) ? svb2[e] : 0.f;
        W3T[e] = (e < 100) ? svW3[e] : 0.f;
    }
    for (int e = tid; e < 512; e += BLOCK) {       // W1f
        const int kc2 = e >> 5, r5 = e & 31, grp = r5 >> 3, kk = kc2 * 8 + (r5 & 7);
        float v = 0.f;
        if (kk < 100) v = (grp == 0) ? svW1[kk] : (grp == 1) ? svW1[100 + kk]
                        : (grp == 2) ? svW1[200 + kk] : svb1[kk];
        W1f[e] = v;
    }
    for (int e = tid; e < 512; e += BLOCK) {       // WH1f
        const int hq = e >> 5, r5 = e & 31, grp = r5 >> 3;
        const int hmm = hq >> 2, qq = hq & 3;
        const int j = qq * 8 + (r5 & 7);
        float v = 0.f;
        if (j < 20 && grp < 3)
            v = (grp == 0) ? vhW1[hmm * 40 + j] : (grp == 1) ? vhW1[hmm * 40 + 20 + j]
                                                : vhb1[hmm * 20 + j];
        WH1f[e] = v;
    }

    // ---- uniform setup -----------------------------------------------------
    const float rate  = ratep[0];
    const float S0    = S0p[0];
    const float rho_t = tanhf(rhop[0]);
    const float srho  = sqrtf(1.f - rho_t * rho_t);
    const float b3    = svb3[0];

    // ---- per-step uniform tables -------------------------------------------
    if (tid < NSTEP) {
        const int i = tid;
        const float t0 = (float)i       * (1.f / 365.f);
        const float t1 = (float)(i + 1) * (1.f / 365.f);
        const float h  = t1 - t0;
        STEP[i] = make_float4(t0, h, sqrtf(h), __expf(-rate * t0));
        D1T[i]  = __expf(-rate * t1);
        const int day = i + 1;
        const int m0 = mats[0], m1 = mats[1], m2 = mats[2], m3 = mats[3];
        const int idx = (day > m0) + (day > m1) + (day > m2);
        const int mi  = (idx == 0) ? m0 : (idx == 1) ? m1 : (idx == 2) ? m2 : m3;
        ITAB[i] = idx | ((day == mi) ? 256 : 0);
    }

    // ---- invariant A-fragments (weights) -----------------------------------
    bf16x8 Af[4][2];
#pragma unroll
    for (int c = 0; c < 4; c++)
#pragma unroll
        for (int t = 0; t < 2; t++) {
            U8 tt;
#pragma unroll
            for (int e2 = 0; e2 < 4; e2++) {
                const int k0 = 32 * c + 8 * quad + 2 * e2;
                const int j  = (2 * jg + t) * 16 + col;
                const float v0 = (k0     < 100 && j < 100) ? svW2[k0 * 100 + j]       : 0.f;
                const float v1 = (k0 + 1 < 100 && j < 100) ? svW2[(k0 + 1) * 100 + j] : 0.f;
                (&tt.u.x)[e2] = bf16rne(v0) | (bf16rne(v1) << 16);
            }
            Af[c][t] = tt.v;
        }
    bf16x8 Ah[2];
#pragma unroll
    for (int st = 0; st < 2; st++) {
        U8 tt;
#pragma unroll
        for (int e2 = 0; e2 < 4; e2++) {
            const int j0 = 8 * quad + 2 * e2, j1 = j0 + 1;
            const int s  = st * 16 + col;
            const float v0 = (j0 < 20 && s < 21) ? vhW2[hm * 420 + j0 * 21 + s] : 0.f;
            const float v1 = (j1 < 20 && s < 21) ? vhW2[hm * 420 + j1 * 21 + s] : 0.f;
            (&tt.u.x)[e2] = bf16rne(v0) | (bf16rne(v1) << 16);
        }
        Ah[st] = tt.v;
    }
    f32x4 c0h, c1h;
    float K0a[4], K1a[4];
#pragma unroll
    for (int r = 0; r < 4; r++) {
        const int s0 = quad * 4 + r, s1 = 16 + quad * 4 + r;
        c0h[r] = vhb2[hm * 21 + s0];
        K0a[r] = strikesg[s0];
        c1h[r] = (s1 < 21) ? vhb2[hm * 21 + s1] : 0.f;
        K1a[r] = (s1 < 21) ? strikesg[s1] : 1e30f;
    }

    // ---- wave-1 register state ---------------------------------------------
    float Slog = __logf(S0);
    float S    = __expf(Slog);
    float V    = (1.f / (1.f + __expf(-v0p[0]))) * 0.5f;
    f32x4 cv0 = {0.f, 0.f, 0.f, 0.f};
    f32x4 cv1 = {0.f, 0.f, 0.f, 0.f};

    const int path = pt * 16 + col;        // P1/B-frag path of this thread
    const int kc   = jg * 4 + quad;        // P1 k-chunk of this thread

    __syncthreads();          // tables staged

    // ---- step-0 folds + LDS state init -------------------------------------
    if (tid < 128) {
        const float t00 = STEP[0].x;
        const int kk = tid;
        CW1[0][kk] = fmaf(t00, W1f[(kk >> 3) * 32 + (kk & 7)],
                               W1f[(kk >> 3) * 32 + 24 + (kk & 7)]);
    } else if (tid < 256) {
        const float t00 = STEP[0].x;
        const int e = tid - 128;
        CH[0][e] = fmaf(t00, WH1f[(e >> 3) * 32 + (e & 7)],
                             WH1f[(e >> 3) * 32 + 16 + (e & 7)]);
    }
    if (tid < 32) {
        SLOG[tid] = Slog;
        SST[tid]  = S;
        VST[tid]  = V;
    }

    __syncthreads();          // folds + state visible

    // invariant epilogue constants -> registers
    const int j0e = (2 * jg) * 16 + quad * 4;
    const float4 b2a = *reinterpret_cast<const float4*>(B2T + j0e);
    const float4 w3a = *reinterpret_cast<const float4*>(W3T + j0e);
    const float4 b2b = *reinterpret_cast<const float4*>(B2T + j0e + 16);
    const float4 w3b = *reinterpret_cast<const float4*>(W3T + j0e + 16);

    auto hedge_step = [&](int ip) {
        const int iv   = ITAB[ip];
        const int idxp = iv & 0xff;
        if (hm >= idxp) {
            const int hb = ip & 1;
            const float slp = SLOGP[path];
            U8 b;
#pragma unroll
            for (int hh = 0; hh < 2; hh++) {
                const float* Wp = WH1f + (hm * 4 + quad) * 32 + 8 + hh * 4;
                const float4 ws4 = *reinterpret_cast<const float4*>(Wp);
                const float4 ch4 = *reinterpret_cast<const float4*>(&CH[hb][(hm * 4 + quad) * 8 + hh * 4]);
                const float x0 = fmaxf(ch4.x + slp * ws4.x, 0.f);
                const float x1 = fmaxf(ch4.y + slp * ws4.y, 0.f);
                const float x2 = fmaxf(ch4.z + slp * ws4.z, 0.f);
                const float x3 = fmaxf(ch4.w + slp * ws4.w, 0.f);
                (&b.u.x)[2 * hh]     = pk2(x0, x1);
                (&b.u.x)[2 * hh + 1] = pk2(x2, x3);
            }
            const f32x4 D0 = __builtin_amdgcn_mfma_f32_16x16x32_bf16(Ah[0], b.v, c0h, 0, 0, 0);
            const f32x4 D1 = __builtin_amdgcn_mfma_f32_16x16x32_bf16(Ah[1], b.v, c1h, 0, 0, 0);
            const float dsP = DSP[path];
#pragma unroll
            for (int r = 0; r < 4; r++) {
                cv0[r] += sp(D0[r]) * dsP;
                cv1[r] += sp(D1[r]) * dsP;
            }
            if ((iv & 256) && hm == idxp) {
                const float Sp  = SST[path];
                const float d1p = D1T[ip];
                float p0[4], q0[4], p1[4], q1[4];
#pragma unroll
                for (int r = 0; r < 4; r++) {
                    p0[r] = d1p * fmaxf(Sp - K0a[r], 0.f) - cv0[r];
                    p1[r] = d1p * fmaxf(Sp - K1a[r], 0.f) - cv1[r];
                    q0[r] = p0[r] * p0[r];
                    q1[r] = p1[r] * p1[r];
                }
#pragma unroll
                for (int o = 1; o <= 8; o <<= 1) {
#pragma unroll
                    for (int r = 0; r < 4; r++) {
                        p0[r] += __shfl_xor(p0[r], o);
                        q0[r] += __shfl_xor(q0[r], o);
                        p1[r] += __shfl_xor(p1[r], o);
                        q1[r] += __shfl_xor(q1[r], o);
                    }
                }
                if (col == 0) {
#pragma unroll
                    for (int r = 0; r < 4; r++) {
                        const int s0 = quad * 4 + r, s1 = 16 + quad * 4 + r;
                        PSs[pt][s0] = p0[r];  PSq[pt][s0] = q0[r];
                        if (s1 < 21) { PSs[pt][s1] = p1[r];  PSq[pt][s1] = q1[r]; }
                    }
                }
            }
        }
    };

    auto ps_reduce = [&](int ip) {
        if (w == 0) {
            const int iv = ITAB[ip];
            if (iv & 256) {
                const int s = lane & 31;
                if (s < 21) {
                    const float* src = (lane >= 32) ? &PSq[0][0] : &PSs[0][0];
                    const float acc = src[s] + src[32 + s];
                    float* dst = (lane >= 32) ? psq : psum;
                    dst[((iv & 0xff) * 21 + s) * NGROUP + blockIdx.x] = acc;
                }
            }
        }
    };

    for (int i = 0; i < NSTEP; i++) {
        const int buf = i & 1;

        // ===== Phase A: P1 h1 chunk | lagged hedge | vd/vv on wave0 =========
        {
            const float slp = SLOG[path];
            const float vp  = VST[path];
            const float* Wp = W1f + kc * 32;
            uint4 o;
#pragma unroll
            for (int hh = 0; hh < 2; hh++) {
                const float4 b4 = *reinterpret_cast<const float4*>(Wp + 8 + hh * 4);
                const float4 c4 = *reinterpret_cast<const float4*>(Wp + 16 + hh * 4);
                const float4 cw = *reinterpret_cast<const float4*>(&CW1[buf][kc * 8 + hh * 4]);
                const float x0 = fmaxf(cw.x + slp * b4.x + vp * c4.x, 0.f);
                const float x1 = fmaxf(cw.y + slp * b4.y + vp * c4.y, 0.f);
                const float x2 = fmaxf(cw.z + slp * b4.z + vp * c4.z, 0.f);
                const float x3 = fmaxf(cw.w + slp * b4.w + vp * c4.w, 0.f);
                (&o.x)[2 * hh]     = pk2(x0, x1);
                (&o.x)[2 * hh + 1] = pk2(x2, x3);
            }
            *reinterpret_cast<uint4*>(H1c + (kc * 32 + path) * 8) = o;
        }
        if (i > 0) hedge_step(i - 1);
        if (w == 0) {                         // vd (lanes<32) / vv (lanes>=32)
            const float Vp = VST[lp];
            const float* bw = VW + ((lane >= 32) ? 64 : 0);
            float a2 = 0.f;
#pragma unroll
            for (int q5 = 0; q5 < 5; q5++) {
                const float4 w1 = *reinterpret_cast<const float4*>(bw + 4 * q5);
                const float4 b1 = *reinterpret_cast<const float4*>(bw + 20 + 4 * q5);
                const float4 w2 = *reinterpret_cast<const float4*>(bw + 40 + 4 * q5);
                a2 += fmaxf(Vp * w1.x + b1.x, 0.f) * w2.x;
                a2 += fmaxf(Vp * w1.y + b1.y, 0.f) * w2.y;
                a2 += fmaxf(Vp * w1.z + b1.z, 0.f) * w2.z;
                a2 += fmaxf(Vp * w1.w + b1.w, 0.f) * w2.w;
            }
            if (lane < 32) VDl[lp] = a2; else VVl[lp] = a2;
        }
        __syncthreads();

        // ===== Phase B: main MFMA + per-lane epilogue =======================
        {
            f32x4 d0 = {0.f, 0.f, 0.f, 0.f};
            f32x4 d1 = {0.f, 0.f, 0.f, 0.f};
#pragma unroll
            for (int c = 0; c < 4; c++) {
                const bf16x8 b = *reinterpret_cast<const bf16x8*>(
                    H1c + ((quad + 4 * c) * 32 + path) * 8);
                d0 = __builtin_amdgcn_mfma_f32_16x16x32_bf16(Af[c][0], b, d0, 0, 0, 0);
                d1 = __builtin_amdgcn_mfma_f32_16x16x32_bf16(Af[c][1], b, d1, 0, 0, 0);
            }
            float acc = fmaxf(d0[0] + b2a.x, 0.f) * w3a.x
                      + fmaxf(d0[1] + b2a.y, 0.f) * w3a.y
                      + fmaxf(d0[2] + b2a.z, 0.f) * w3a.z
                      + fmaxf(d0[3] + b2a.w, 0.f) * w3a.w
                      + fmaxf(d1[0] + b2b.x, 0.f) * w3b.x
                      + fmaxf(d1[1] + b2b.y, 0.f) * w3b.y
                      + fmaxf(d1[2] + b2b.z, 0.f) * w3b.z
                      + fmaxf(d1[3] + b2b.w, 0.f) * w3b.w;
            acc += __shfl_xor(acc, 16);
            acc += __shfl_xor(acc, 32);
            if (quad == 0)
                RED[path * 4 + jg] = acc;
        }
        if (i > 0) ps_reduce(i - 1);
        __syncthreads();

        // ===== Phase C: R3 on wave 1 | next-step folds on waves 2-5 =========
        if (w == 1) {
            const float4 rr = *reinterpret_cast<const float4*>(RED + lp * 4);
            const float pout = (rr.x + rr.y) + (rr.z + rr.w);
            const float pd = sp(pout + b3);
            const float vdv = VDl[lp] + VW[124];
            const float vvv = sp(VVl[lp] + VW[125]);
            const float4 u  = STEP[i];
            const float sqh = u.z;
            const float zi  = ZT[lp][i];
            const float zzi = ZZT[lp][i];
            const float dW = sqh * zi;
            const float dB = rho_t * dW + srho * sqh * zzi;
            const float Vn = V + vdv * u.y + vvv * dB;
            const float drift   = rate - 0.5f * pd * pd;
            const float diff    = pd * dW;
            const float drift_c = 1.f + fabsf(drift) * sqh;
            const float diff_c  = 1.f + fabsf(pd) * sqh;
            const float Sln = Slog + __fdividef(drift * u.y, drift_c) + __fdividef(diff, diff_c);
            const float Sn  = __expf(Sln);
            const float dS  = D1T[i] * Sn - u.w * S;
            if (lane < 32) {
                SLOGP[lp] = Slog;  DSP[lp] = dS;
                SLOG[lp]  = Sln;   SST[lp] = Sn;  VST[lp] = Vn;
            }
            Slog = Sln; S = Sn; V = Vn;
        } else if ((w == 2 || w == 3) && i + 1 < NSTEP) {
            const float t0n = STEP[i + 1].x;
            const int kk = (w - 2) * 64 + lane;
            CW1[buf ^ 1][kk] = fmaf(t0n, W1f[(kk >> 3) * 32 + (kk & 7)],
                                         W1f[(kk >> 3) * 32 + 24 + (kk & 7)]);
        } else if ((w == 4 || w == 5) && i + 1 < NSTEP) {
            const float t0n = STEP[i + 1].x;
            const int e = (w - 4) * 64 + lane;
            CH[buf ^ 1][e] = fmaf(t0n, WH1f[(e >> 3) * 32 + (e & 7)],
                                       WH1f[(e >> 3) * 32 + 16 + (e & 7)]);
        }
        __syncthreads();
    }

    hedge_step(NSTEP - 1);
    __syncthreads();
    ps_reduce(NSTEP - 1);
}

__global__ void lsv_finalize(const float* __restrict__ psum,
                             const float* __restrict__ psq,
                             float* __restrict__ out)
{
    const int t    = blockIdx.x;          // 0..NPAIR-1
    const int lane = threadIdx.x;         // 0..63
    float s = 0.f, q = 0.f;
    for (int b = lane; b < NGROUP; b += 64) {
        s += psum[t * NGROUP + b];
        q += psq [t * NGROUP + b];
    }
#pragma unroll
    for (int o = 1; o <= 32; o <<= 1) {
        s += __shfl_xor(s, o);
        q += __shfl_xor(q, o);
    }
    if (lane == 0) {
        const float mean = s * (1.0f / (float)MC);
        const float var  = (q - (float)MC * mean * mean) * (1.0f / (float)(MC - 1));
        out[t]         = mean;
        out[NPAIR + t] = var;
    }
}

extern "C" void kernel_launch(void* const* d_in, const int* in_sizes, int n_in,
                              void* d_out, int out_size, void* d_ws, size_t ws_size,
                              hipStream_t stream)
{
    const float* S0    = (const float*)d_in[0];
    const float* rate  = (const float*)d_in[1];
    const float* z     = (const float*)d_in[2];
    const float* zz    = (const float*)d_in[3];
    const float* strikes = (const float*)d_in[5];
    const float* v0    = (const float*)d_in[6];
    const float* rho   = (const float*)d_in[7];
    const float* svW1  = (const float*)d_in[8];
    const float* svb1  = (const float*)d_in[9];
    const float* svW2  = (const float*)d_in[10];
    const float* svb2  = (const float*)d_in[11];
    const float* svW3  = (const float*)d_in[12];
    const float* svb3  = (const float*)d_in[13];
    const float* vhW1  = (const float*)d_in[14];
    const float* vhb1  = (const float*)d_in[15];
    const float* vhW2  = (const float*)d_in[16];
    const float* vhb2  = (const float*)d_in[17];
    const float* vdW1  = (const float*)d_in[18];
    const float* vdb1  = (const float*)d_in[19];
    const float* vdW2  = (const float*)d_in[20];
    const float* vdb2  = (const float*)d_in[21];
    const float* vvW1  = (const float*)d_in[22];
    const float* vvb1  = (const float*)d_in[23];
    const float* vvW2  = (const float*)d_in[24];
    const float* vvb2  = (const float*)d_in[25];
    const int*   mats  = (const int*)d_in[26];

    float* psum = (float*)d_ws;
    float* psq  = psum + NPAIR * NGROUP;

    hipLaunchKernelGGL(lsv_sim, dim3(NGROUP), dim3(BLOCK), 0, stream,
                       S0, rate, z, zz, strikes, v0, rho,
                       svW1, svb1, svW2, svb2, svW3, svb3,
                       vhW1, vhb1, vhW2, vhb2,
                       vdW1, vdb1, vdW2, vdb2,
                       vvW1, vvb1, vvW2, vvb2,
                       mats, psum, psq);

    hipLaunchKernelGGL(lsv_finalize, dim3(NPAIR), dim3(64), 0, stream,
                       psum, psq, (float*)d_out);
}